// Round 14
// baseline (992.617 us; speedup 1.0000x reference)
//
#include <hip/hip_runtime.h>
#include <cstdint>
#include <cstddef>

typedef __bf16 bf16;
typedef __bf16 bf16x4 __attribute__((ext_vector_type(4)));
typedef __bf16 bf16x8 __attribute__((ext_vector_type(8)));
typedef float f32x4 __attribute__((ext_vector_type(4)));

#define L_SEQ   1024
#define DMODEL  512
#define DINNER  1024
#define DSTATE  16
#define NHEADS  16
#define HEADDIM 64
#define CONVDIM 1056
#define DINPROJ 2096
#define FFN_DIM 2048
#define ROWS    2048   // B*L
#define CHUNK   32     // scan chunk (was 64): 2048 waves -> 2 waves/SIMD
#define NCHUNK  32
#define SLAB    ((size_t)ROWS * DMODEL)

__device__ __forceinline__ float wave_sum(float v) {
#pragma unroll
  for (int off = 32; off; off >>= 1) v += __shfl_down(v, off, 64);
  return v;
}
__device__ __forceinline__ float silu_f(float x) { return x / (1.0f + expf(-x)); }

// ---------------- RMS norm (+pe/mask), bf16 out (used once, layer 0) -------
__global__ __launch_bounds__(128) void rms_kernel(
    const float* __restrict__ x, const float* __restrict__ w,
    const float* __restrict__ pe, const float* __restrict__ mask,
    bf16* __restrict__ outb)
{
  int r = blockIdx.x, t = threadIdx.x;
  float4 v = ((const float4*)(x + (size_t)r * DMODEL))[t];
  float ss = v.x*v.x + v.y*v.y + v.z*v.z + v.w*v.w;
  ss = wave_sum(ss);
  __shared__ float red[2];
  if ((t & 63) == 0) red[t >> 6] = ss;
  __syncthreads();
  float rs = 1.0f / sqrtf((red[0] + red[1]) * (1.0f / DMODEL) + 1e-6f);
  float4 wv = ((const float4*)w)[t];
  float4 p = ((const float4*)(pe + (size_t)r * DMODEL))[t];
  float m = mask[r];
  bf16x4 o;
  o[0] = (bf16)((v.x*rs*wv.x + p.x) * m);
  o[1] = (bf16)((v.y*rs*wv.y + p.y) * m);
  o[2] = (bf16)((v.z*rs*wv.z + p.z) * m);
  o[3] = (bf16)((v.w*rs*wv.w + p.w) * m);
  *(bf16x4*)&outb[(size_t)r * DMODEL + t * 4] = o;
}

// ------- transpose+cvt ALL weights, ONE dispatch (frozen: HBM-pattern-bound)
__global__ __launch_bounds__(256) void transpose_all(
    const float* __restrict__ W_in, const float* __restrict__ W_out,
    const float* __restrict__ f1, const float* __restrict__ f2,
    bf16* __restrict__ TIN, bf16* __restrict__ TOUT,
    bf16* __restrict__ T1, bf16* __restrict__ T2)
{
  int bid = blockIdx.x;
  const float* src; bf16* dst; int K, N, k0, n0;
  if (bid < 3168) {                  // W_in: 12 x (4 kt x 66 nt)
    int slice = bid / 264, rem = bid % 264;
    K = 512; N = 2096;
    k0 = (rem & 3) * 128; n0 = (rem >> 2) * 32;
    src = W_in + (size_t)slice * K * N;  dst = TIN + (size_t)slice * N * K;
  } else if (bid < 4704) {           // W_out: 12 x (8 kt x 16 nt)
    int t2 = bid - 3168;
    int slice = t2 / 128, rem = t2 % 128;
    K = 1024; N = 512;
    k0 = (rem & 7) * 128; n0 = (rem >> 3) * 32;
    src = W_out + (size_t)slice * K * N; dst = TOUT + (size_t)slice * N * K;
  } else if (bid < 6240) {           // ffn1: 6 x (4 kt x 64 nt)
    int t3 = bid - 4704;
    int slice = t3 / 256, rem = t3 % 256;
    K = 512; N = 2048;
    k0 = (rem & 3) * 128; n0 = (rem >> 2) * 32;
    src = f1 + (size_t)slice * K * N;    dst = T1 + (size_t)slice * N * K;
  } else {                           // ffn2: 6 x (16 kt x 16 nt)
    int t4 = bid - 6240;
    int slice = t4 / 256, rem = t4 % 256;
    K = 2048; N = 512;
    k0 = (rem & 15) * 128; n0 = (rem >> 4) * 32;
    src = f2 + (size_t)slice * K * N;    dst = T2 + (size_t)slice * N * K;
  }
  __shared__ float tile[128][33];
  int fq = threadIdx.x & 7, kr = threadIdx.x >> 3;
#pragma unroll
  for (int p = 0; p < 4; p++) {
    int k = kr + 32 * p;
    float4 v = {0.0f, 0.0f, 0.0f, 0.0f};
    int n = n0 + fq * 4;
    if (n < N) v = *(const float4*)&src[(size_t)(k0 + k) * N + n];
    int cq = (fq * 4) ^ (((k >> 3) & 7) << 2);   // swizzled quad base
    *(float4*)&tile[k][cq] = v;
  }
  __syncthreads();
  int kg = threadIdx.x & 15, nb = threadIdx.x >> 4;
#pragma unroll
  for (int p = 0; p < 2; p++) {
    int nn = nb + 16 * p;
    if (n0 + nn < N) {
      bf16x8 o;
#pragma unroll
      for (int j = 0; j < 8; j++) {
        int row = kg * 8 + j;
        o[j] = (bf16)tile[row][nn ^ (((row >> 3) & 7) << 2)];
      }
      *(bf16x8*)&dst[(size_t)(n0 + nn) * K + k0 + kg * 8] = o;
    }
  }
}

// ---------------- bf16 MFMA GEMM, BK=64 two-half LDS, gload_lds staging ----
// MODE 0: f32 out  MODE 1: +bias,gelu,bf16 out  MODE 3: bf16 out + f32 dt tail
// z axis = dir * kspl + ks
template<int BM, int BN, int FI, int FJ, int MODE>
__global__ __launch_bounds__(256) void gemm_tile(
    const bf16* __restrict__ A, const bf16* __restrict__ BT,
    float* __restrict__ Cf, bf16* __restrict__ Cb,
    int M, int N, int K, int lda, int ldb,
    long aOffz, long bOffz, long cOffz, int flipz, int kspl,
    const float* __restrict__ bias)
{
  constexpr int CH = (BM + BN) * 8;        // 16B chunks per 64-k step
  constexpr int NI = CH / 256;             // gload_lds per thread-group pass
  constexpr int HC = CH / 2;               // chunks per 32-k half
  constexpr int HALF = (BM + BN) * 32;     // bf16 elems per half buffer

  int z = blockIdx.z;
  int dir = z / kspl, ks = z - dir * kspl;
  A  += (size_t)dir * aOffz + (size_t)ks * K;
  BT += (size_t)dir * bOffz + (size_t)ks * K;
  long coff = (size_t)z * cOffz;
  int doflip = (flipz && dir == 1);

  __shared__ __align__(16) bf16 Tile[2 * HALF];

  int m0 = blockIdx.x * BM, n0 = blockIdx.y * BN;
  int t = threadIdx.x;
  int lane = t & 63, w = t >> 6;
  int wr = w >> 1, wc = w & 1;
  int lr = lane & 15, lq = lane >> 4;

  const bf16* gsrc[NI];
  int ldsoff[NI];
#pragma unroll
  for (int i = 0; i < NI; i++) {
    int g0 = w * (CH / 4) + i * 64;        // wave-uniform chunk base
    int g  = g0 + lane;
    int half = g / HC;                     // whole 64-chunk run same half
    int wi = g - half * HC;
    int row = wi >> 2, kp = wi & 3;
    int kcol = half * 32 + kp * 8;
    if (row < BM) {
      int gr = m0 + row;
      if (doflip) gr ^= (L_SEQ - 1);
      gsrc[i] = A + (size_t)gr * lda + kcol;
    } else {
      int gn = n0 + (row - BM); if (gn >= N) gn = N - 1;
      gsrc[i] = BT + (size_t)gn * ldb + kcol;
    }
    int half0 = g0 / HC, wi0 = g0 - half0 * HC;
    ldsoff[i] = half0 * HALF + wi0 * 8;
  }

  f32x4 zf = {0.0f, 0.0f, 0.0f, 0.0f};
  f32x4 acc[FI][FJ];
#pragma unroll
  for (int i = 0; i < FI; i++)
#pragma unroll
    for (int j = 0; j < FJ; j++) acc[i][j] = zf;

  for (int k0 = 0; k0 < K; k0 += 64) {
#pragma unroll
    for (int i = 0; i < NI; i++) {
      __builtin_amdgcn_global_load_lds(
          (const __attribute__((address_space(1))) void*)(gsrc[i] + k0),
          (__attribute__((address_space(3))) void*)&Tile[ldsoff[i]],
          16, 0, 0);
    }
    __syncthreads();

#pragma unroll
    for (int hf = 0; hf < 2; hf++) {
      const bf16* As = Tile + hf * HALF;
      const bf16* Bs = As + BM * 32;
      bf16x8 af[FI], bfv[FJ];
#pragma unroll
      for (int i = 0; i < FI; i++)
        af[i] = *(const bf16x8*)&As[(wr * 64 + i * 16 + lr) * 32 + lq * 8];
#pragma unroll
      for (int j = 0; j < FJ; j++)
        bfv[j] = *(const bf16x8*)&Bs[(wc * (BN / 2) + j * 16 + lr) * 32 + lq * 8];
#pragma unroll
      for (int i = 0; i < FI; i++)
#pragma unroll
        for (int j = 0; j < FJ; j++)
          acc[i][j] = __builtin_amdgcn_mfma_f32_16x16x32_bf16(af[i], bfv[j], acc[i][j], 0, 0, 0);
    }
    __syncthreads();
  }

#pragma unroll
  for (int i = 0; i < FI; i++) {
    int growb = m0 + wr * 64 + i * 16 + lq * 4;
#pragma unroll
    for (int j = 0; j < FJ; j++) {
      int gcol = n0 + wc * (BN / 2) + j * 16 + lr;
      if (gcol >= N) continue;
#pragma unroll
      for (int rr = 0; rr < 4; rr++) {
        int grow = growb + rr;
        float v = acc[i][j][rr];
        if (MODE == 1) {
          v += bias[gcol];
          v = 0.5f * v * (1.0f + erff(v * 0.70710678118f));
          Cb[coff + (size_t)grow * N + gcol] = (bf16)v;
        } else if (MODE == 3) {
          Cb[coff + (size_t)grow * N + gcol] = (bf16)v;
          if (gcol >= DINNER + CONVDIM)
            Cf[(size_t)z * ROWS * 16 + (size_t)grow * 16 + (gcol - (DINNER + CONVDIM))] = v;
        } else {
          Cf[coff + (size_t)grow * N + gcol] = v;
        }
      }
    }
  }
}

// ------ conv+silu for the 32 B/C channels only (compact f32 out) + dt/dA ----
__global__ __launch_bounds__(64) void convdt_bc(
    const bf16* __restrict__ ZX, const float* __restrict__ DTRAW,
    float* __restrict__ BCf, float* __restrict__ DT, float* __restrict__ DA,
    const float* __restrict__ conv_w, const float* __restrict__ conv_b,
    const float* __restrict__ dt_bias, const float* __restrict__ A_log)
{
  int r = blockIdx.x, dir = blockIdx.y;
  int l = r & (L_SEQ - 1);
  int t = threadIdx.x;
  if (t < 32) {
    int ch = DINNER + t;             // conv channel 1024+t (B/C block)
    const float* cw = conv_w + ((size_t)dir * CONVDIM + ch) * 4;
    float acc = conv_b[(size_t)dir * CONVDIM + ch];
    const bf16* zc = ZX + (size_t)dir * ROWS * DINPROJ + DINNER + ch;
#pragma unroll
    for (int k = 0; k < 4; k++) {
      int ls = l + k - 3;
      if (ls >= 0) acc += (float)zc[(size_t)(r + k - 3) * DINPROJ] * cw[k];
    }
    BCf[((size_t)dir * ROWS + r) * 32 + t] = silu_f(acc);
  } else if (t < 48) {
    int h = t - 32;
    float raw = DTRAW[((size_t)dir * ROWS + r) * 16 + h] + dt_bias[dir * NHEADS + h];
    float dt = (raw > 20.0f) ? raw : log1pf(expf(raw));
    float A = -expf(A_log[dir * NHEADS + h]);
    size_t idx = ((size_t)dir * ROWS + r) * NHEADS + h;
    DT[idx] = dt;
    DA[idx] = expf(dt * A);
  }
}

// ---- chunked SSM scan pass 1 (CHUNK=32): inline x-conv + local scan.
//      One wave per (dir,b,head,chunk); lanes 0..31 carry dt/dA rows. ----
__global__ __launch_bounds__(64) void scan1_kernel(
    const bf16* __restrict__ ZX, const float* __restrict__ BCf,
    const float* __restrict__ DT, const float* __restrict__ DA,
    bf16* __restrict__ YSSM, float* __restrict__ HEND,
    float* __restrict__ APROD,
    const float* __restrict__ conv_w, const float* __restrict__ conv_b,
    const float* __restrict__ Dparam)
{
  int bid = blockIdx.x;              // 2048 blocks
  int g = bid >> 5, c = bid & 31;
  int dir = g >> 5, rem = g & 31;
  int b = rem >> 4, h = rem & 15;
  int lane = threadIdx.x;
  int lrow = lane & 31;
  size_t rowbase = (size_t)dir * ROWS + b * L_SEQ + c * CHUNK;

  float dtv = DT[(rowbase + lrow) * NHEADS + h];
  float dav = DA[(rowbase + lrow) * NHEADS + h];

  // width-32 inclusive prefix product (both halves duplicate)
  float ap = dav;
#pragma unroll
  for (int off = 1; off < 32; off <<= 1) {
    float o = __shfl_up(ap, off, 32);
    if (lrow >= off) ap *= o;
  }
  if (lane < 32) APROD[((size_t)g * NCHUNK + c) * 32 + lrow] = ap;

  // stage conv'd B|C (32 f32/row) into LDS: 32 rows x 8 float4 = 4 iters
  __shared__ float BCs[CHUNK][36];
#pragma unroll
  for (int i = 0; i < 4; i++) {
    int idx = i * 64 + lane;
    int l = idx >> 3, f = idx & 7;
    float4 v = *(const float4*)&BCf[(rowbase + l) * 32 + f * 4];
    *(float4*)&BCs[l][f * 4] = v;
  }
  __syncthreads();

  // x-conv setup: lane owns channel ch = h*64+lane; sliding 4-tap window
  int ch = h * HEADDIM + lane;
  f32x4 cwv = *(const f32x4*)&conv_w[((size_t)dir * CONVDIM + ch) * 4];
  float cbv = conv_b[(size_t)dir * CONVDIM + ch];
  const bf16* xcol = ZX + rowbase * DINPROJ + DINNER + ch;  // stride DINPROJ
  int lg0 = c * CHUNK;   // global seq pos of chunk start
  float xm3 = (lg0 >= 3) ? (float)xcol[-3 * DINPROJ] : 0.0f;
  float xm2 = (lg0 >= 2) ? (float)xcol[-2 * DINPROJ] : 0.0f;
  float xm1 = (lg0 >= 1) ? (float)xcol[-1 * DINPROJ] : 0.0f;

  float Dv = Dparam[dir * NHEADS + h];

  float hs[16];
#pragma unroll
  for (int n = 0; n < 16; n++) hs[n] = 0.0f;

  bf16* yp = YSSM + rowbase * DINNER + ch;

#pragma unroll 4
  for (int l = 0; l < CHUNK; l++) {
    float dt = __shfl(dtv, l, 64);
    float da = __shfl(dav, l, 64);
    float xcur = (float)xcol[(size_t)l * DINPROJ];
    float conv = cbv + cwv[0]*xm3 + cwv[1]*xm2 + cwv[2]*xm1 + cwv[3]*xcur;
    xm3 = xm2; xm2 = xm1; xm1 = xcur;
    float xv = silu_f(conv);
    float4 bq[4], cq[4];
#pragma unroll
    for (int q = 0; q < 4; q++) {
      bq[q] = *(const float4*)&BCs[l][q * 4];
      cq[q] = *(const float4*)&BCs[l][16 + q * 4];
    }
    const float* Bv = (const float*)bq;
    const float* Cv = (const float*)cq;
    float dtx = dt * xv;
    float acc = 0.0f;
#pragma unroll
    for (int n = 0; n < 16; n++) {
      hs[n] = hs[n] * da + dtx * Bv[n];
      acc += hs[n] * Cv[n];
    }
    yp[(size_t)l * DINNER] = (bf16)(acc + Dv * xv);
  }

  float* he = HEND + ((size_t)g * NCHUNK + c) * 16 * 64;
#pragma unroll
  for (int n = 0; n < 16; n++) he[n * 64 + lane] = hs[n];
}

// ---------------- chunked SSM scan, pass 2: cross-chunk correction --------
__global__ __launch_bounds__(64) void scan2_kernel(
    const float* __restrict__ BCf, bf16* __restrict__ YSSM,
    const float* __restrict__ HEND, const float* __restrict__ APROD)
{
  int bid = blockIdx.x;
  int g = bid >> 5, c = bid & 31;
  if (c == 0) return;
  int dir = g >> 5, rem = g & 31;
  int b = rem >> 4, h = rem & 15;
  int lane = threadIdx.x;

  float hstart[16];
#pragma unroll
  for (int n = 0; n < 16; n++) hstart[n] = 0.0f;
  float w = 1.0f;
  for (int j = c - 1; j >= 0; j--) {
    const float* he = HEND + ((size_t)g * NCHUNK + j) * 16 * 64;
#pragma unroll
    for (int n = 0; n < 16; n++) hstart[n] += w * he[n * 64 + lane];
    w *= APROD[((size_t)g * NCHUNK + j) * 32 + 31];
  }

  size_t rowbase = (size_t)dir * ROWS + b * L_SEQ + c * CHUNK;
  bf16* yp = YSSM + rowbase * DINNER + h * HEADDIM + lane;
  float apv = APROD[((size_t)g * NCHUNK + c) * 32 + (lane & 31)];

  // stage C (16 f32/row): 32 rows x 4 float4 = 2 iters
  __shared__ float Cs[CHUNK][20];
#pragma unroll
  for (int i = 0; i < 2; i++) {
    int idx = i * 64 + lane;
    int l = idx >> 2, f = idx & 3;
    float4 v = *(const float4*)&BCf[(rowbase + l) * 32 + 16 + f * 4];
    *(float4*)&Cs[l][f * 4] = v;
  }
  __syncthreads();

#pragma unroll 4
  for (int l = 0; l < CHUNK; l++) {
    float a = __shfl(apv, l, 64);
    float4 cq[4];
#pragma unroll
    for (int q = 0; q < 4; q++) cq[q] = *(const float4*)&Cs[l][q * 4];
    const float* Cv = (const float*)cq;
    float acc = 0.0f;
#pragma unroll
    for (int n = 0; n < 16; n++) acc += Cv[n] * hstart[n];
    float y = (float)yp[(size_t)l * DINNER];
    yp[(size_t)l * DINNER] = (bf16)(y + a * acc);
  }
}

// ------- gate (y already has D*x): y*silu(z) + RMS(1024), bf16 out -------
__global__ __launch_bounds__(256) void gatenorm_kernel(
    const bf16* __restrict__ YSSM, const bf16* __restrict__ ZX,
    const float* __restrict__ mnorm_w, bf16* __restrict__ YB)
{
  int r = blockIdx.x, dir = blockIdx.y, t = threadIdx.x;
  const bf16* y = YSSM + ((size_t)dir * ROWS + r) * DINNER;
  const bf16* z  = ZX  + ((size_t)dir * ROWS + r) * DINPROJ;
  int c = t * 4;
  bf16x4 yv4 = *(const bf16x4*)&y[c];
  bf16x4 zv4 = *(const bf16x4*)&z[c];
  float val[4];
#pragma unroll
  for (int q = 0; q < 4; q++)
    val[q] = (float)yv4[q] * silu_f((float)zv4[q]);
  float ss = val[0]*val[0] + val[1]*val[1] + val[2]*val[2] + val[3]*val[3];
  ss = wave_sum(ss);
  __shared__ float red[4];
  if ((t & 63) == 0) red[t >> 6] = ss;
  __syncthreads();
  float total = red[0] + red[1] + red[2] + red[3];
  float rs = 1.0f / sqrtf(total * (1.0f / DINNER) + 1e-5f);
  float4 wv = *(const float4*)&mnorm_w[dir * DINNER + c];
  bf16x4 o;
  o[0] = (bf16)(val[0] * rs * wv.x);
  o[1] = (bf16)(val[1] * rs * wv.y);
  o[2] = (bf16)(val[2] * rs * wv.z);
  o[3] = (bf16)(val[3] * rs * wv.w);
  *(bf16x4*)&YB[((size_t)dir * ROWS + r) * DINNER + c] = o;
}

// ------ combine (x += 0.5*(f+flip(b))*mask) + FFN RMS, bf16 out ------
__global__ __launch_bounds__(128) void combine_rms(
    const float* __restrict__ Xsrc, float* __restrict__ X,
    const float* __restrict__ P, const float* __restrict__ mask,
    const float* __restrict__ w, bf16* __restrict__ outb)
{
  int r = blockIdx.x, t = threadIdx.x;
  int b = r >> 10, l = r & 1023;
  int c = t * 4;
  float m = 0.5f * mask[r];
  float4 f0 = *(const float4*)&P[(size_t)r * DMODEL + c];
  float4 f1 = *(const float4*)&P[SLAB + (size_t)r * DMODEL + c];
  size_t fr = (size_t)(b * L_SEQ + (L_SEQ - 1 - l)) * DMODEL + c;
  float4 b0 = *(const float4*)&P[2 * SLAB + fr];
  float4 b1 = *(const float4*)&P[3 * SLAB + fr];
  float4 x = *(const float4*)&Xsrc[(size_t)r * DMODEL + c];
  x.x += m * (f0.x + f1.x + b0.x + b1.x);
  x.y += m * (f0.y + f1.y + b0.y + b1.y);
  x.z += m * (f0.z + f1.z + b0.z + b1.z);
  x.w += m * (f0.w + f1.w + b0.w + b1.w);
  *(float4*)&X[(size_t)r * DMODEL + c] = x;
  float ss = x.x*x.x + x.y*x.y + x.z*x.z + x.w*x.w;
  ss = wave_sum(ss);
  __shared__ float red[2];
  if ((t & 63) == 0) red[t >> 6] = ss;
  __syncthreads();
  float rs = 1.0f / sqrtf((red[0] + red[1]) * (1.0f / DMODEL) + 1e-6f);
  float4 wv = *(const float4*)&w[c];
  bf16x4 o;
  o[0] = (bf16)(x.x * rs * wv.x);
  o[1] = (bf16)(x.y * rs * wv.y);
  o[2] = (bf16)(x.z * rs * wv.z);
  o[3] = (bf16)(x.w * rs * wv.w);
  *(bf16x4*)&outb[(size_t)r * DMODEL + c] = o;
}

// ------ FFN2 splitK reduce (4 slabs) + bias + resid, then RMS ---
__global__ __launch_bounds__(128) void reduce_rms(
    float* __restrict__ X, const float* __restrict__ P,
    const float* __restrict__ bias, const float* __restrict__ w,
    const float* __restrict__ pe, const float* __restrict__ mask,
    bf16* __restrict__ outb, float* __restrict__ outf)
{
  int r = blockIdx.x, t = threadIdx.x;
  int c = t * 4;
  size_t off = (size_t)r * DMODEL + c;
  float4 a0 = *(const float4*)&P[off];
  float4 a1 = *(const float4*)&P[SLAB + off];
  float4 a2 = *(const float4*)&P[2 * SLAB + off];
  float4 a3 = *(const float4*)&P[3 * SLAB + off];
  float4 bi = *(const float4*)&bias[c];
  float4 x  = *(float4*)&X[off];
  x.x += a0.x + a1.x + a2.x + a3.x + bi.x;
  x.y += a0.y + a1.y + a2.y + a3.y + bi.y;
  x.z += a0.z + a1.z + a2.z + a3.z + bi.z;
  x.w += a0.w + a1.w + a2.w + a3.w + bi.w;
  *(float4*)&X[off] = x;
  float ss = x.x*x.x + x.y*x.y + x.z*x.z + x.w*x.w;
  ss = wave_sum(ss);
  __shared__ float red[2];
  if ((t & 63) == 0) red[t >> 6] = ss;
  __syncthreads();
  float rs = 1.0f / sqrtf((red[0] + red[1]) * (1.0f / DMODEL) + 1e-6f);
  float4 wv = *(const float4*)&w[c];
  float4 o;
  o.x = x.x*rs*wv.x; o.y = x.y*rs*wv.y; o.z = x.z*rs*wv.z; o.w = x.w*rs*wv.w;
  if (pe) {
    float4 p = *(const float4*)&pe[off];
    float m = mask[r];
    o.x = (o.x + p.x)*m; o.y = (o.y + p.y)*m; o.z = (o.z + p.z)*m; o.w = (o.w + p.w)*m;
  }
  if (outb) {
    bf16x4 ob = {(bf16)o.x, (bf16)o.y, (bf16)o.z, (bf16)o.w};
    *(bf16x4*)&outb[off] = ob;
  } else {
    *(float4*)&outf[off] = o;
  }
}

// ---------------- host ----------------
extern "C" void kernel_launch(void* const* d_in, const int* in_sizes, int n_in,
                              void* d_out, int out_size, void* d_ws, size_t ws_size,
                              hipStream_t stream)
{
  const float* in_x    = (const float*)d_in[0];
  const float* in_pe   = (const float*)d_in[1];
  const float* in_mask = (const float*)d_in[2];
  const float* W_in    = (const float*)d_in[3];
  const float* conv_w  = (const float*)d_in[4];
  const float* conv_b  = (const float*)d_in[5];
  const float* A_log   = (const float*)d_in[6];
  const float* Dparam  = (const float*)d_in[7];
  const float* dt_bias = (const float*)d_in[8];
  const float* mnorm_w = (const float*)d_in[9];
  const float* W_out   = (const float*)d_in[10];
  const float* nssm_w  = (const float*)d_in[11];
  const float* ffn_w1  = (const float*)d_in[12];
  const float* ffn_b1  = (const float*)d_in[13];
  const float* ffn_w2  = (const float*)d_in[14];
  const float* ffn_b2  = (const float*)d_in[15];
  const float* nffn_w  = (const float*)d_in[16];
  const float* final_w = (const float*)d_in[17];

  if (ws_size < 126287872) return;

  // workspace layout. DOUT (4 f32 slabs, 16.78MB) OVERLAYS ZXb (verified).
  // HEND now 8MB (NCHUNK=32): 49938432..58327040; APROD 256KB after it.
  char* ws = (char*)d_ws;
  float* XBUF  = (float*)(ws + 0);            //  4,194,304
  bf16*  SBUF  = (bf16*) (ws + 4194304);      //  2,097,152
  bf16*  ZXb   = (bf16*) (ws + 6291456);      // 17,170,432
  float* DOUTf = (float*)(ws + 6291456);      // 16,777,216 (alias of ZXb)
  float* DTRAW = (float*)(ws + 23461888);     //    262,144
  float* BCf   = (float*)(ws + 23724032);     //    524,288
  float* DTb   = (float*)(ws + 24248320);     //    262,144
  float* DAb   = (float*)(ws + 24510464);     //    262,144
  bf16*  YSSMb = (bf16*) (ws + 24772608);     //  8,388,608
  bf16*  YB    = (bf16*) (ws + 33161216);     //  8,388,608
  bf16*  MID   = (bf16*) (ws + 41549824);     //  8,388,608
  float* HEND  = (float*)(ws + 49938432);     //  8,388,608 -> 58,327,040
  float* APROD = (float*)(ws + 58327040);     //    262,144 -> 58,589,184
  bf16*  WTINa = (bf16*) (ws + 62783488);     // 25,755,648
  bf16*  WTOUTa= (bf16*) (ws + 88539136);     // 12,582,912
  bf16*  WT1a  = (bf16*) (ws + 101122048);    // 12,582,912
  bf16*  WT2a  = (bf16*) (ws + 113704960);    // 12,582,912 -> 126,287,872

  transpose_all<<<7776, 256, 0, stream>>>(W_in, W_out, ffn_w1, ffn_w2,
                                          WTINa, WTOUTa, WT1a, WT2a);
  rms_kernel<<<ROWS, 128, 0, stream>>>(in_x, nssm_w, in_pe, in_mask, SBUF);

  for (int layer = 0; layer < 6; layer++) {
    const bf16* WTIN  = WTINa  + (size_t)layer * 2 * DMODEL * DINPROJ;
    const bf16* WTOUT = WTOUTa + (size_t)layer * 2 * DINNER * DMODEL;
    const bf16* WT1   = WT1a   + (size_t)layer * DMODEL * FFN_DIM;
    const bf16* WT2   = WT2a   + (size_t)layer * FFN_DIM * DMODEL;
    const float* cw_l = conv_w + (size_t)layer * 2 * CONVDIM * 4;
    const float* cb_l = conv_b + (size_t)layer * 2 * CONVDIM;

    gemm_tile<128, 128, 4, 4, 3><<<dim3(16, 17, 2), 256, 0, stream>>>(
        SBUF, WTIN, DTRAW, ZXb, ROWS, DINPROJ, DMODEL, DMODEL, DMODEL,
        0L, (long)DINPROJ * DMODEL, (long)ROWS * DINPROJ, 1, 1, nullptr);
    convdt_bc<<<dim3(ROWS, 2), 64, 0, stream>>>(
        ZXb, DTRAW, BCf, DTb, DAb, cw_l, cb_l,
        dt_bias + layer * 2 * NHEADS, A_log + layer * 2 * NHEADS);
    scan1_kernel<<<2048, 64, 0, stream>>>(
        ZXb, BCf, DTb, DAb, YSSMb, HEND, APROD, cw_l, cb_l,
        Dparam + layer * 2 * NHEADS);
    scan2_kernel<<<2048, 64, 0, stream>>>(BCf, YSSMb, HEND, APROD);
    gatenorm_kernel<<<dim3(ROWS, 2), 256, 0, stream>>>(
        YSSMb, ZXb, mnorm_w + layer * 2 * DINNER, YB);
    // W_out: z = dir*2 + ks (kspl=2, K=512 each) -> 512 blocks, 2/CU
    gemm_tile<128, 64, 4, 2, 0><<<dim3(16, 8, 4), 256, 0, stream>>>(
        YB, WTOUT, DOUTf, nullptr, ROWS, DMODEL, 512, DINNER, DINNER,
        (long)ROWS * DINNER, (long)DMODEL * DINNER, (long)SLAB, 0, 2, nullptr);
    combine_rms<<<ROWS, 128, 0, stream>>>(
        layer == 0 ? in_x : XBUF, XBUF, DOUTf, in_mask, nffn_w + layer * DMODEL, SBUF);

    // FFN
    gemm_tile<128, 64, 4, 2, 1><<<dim3(16, 32, 1), 256, 0, stream>>>(
        SBUF, WT1, nullptr, MID, ROWS, FFN_DIM, DMODEL, DMODEL, DMODEL,
        0L, 0L, 0L, 0, 1, ffn_b1 + layer * FFN_DIM);
    // FFN2: kspl=4 (K=512 each) -> 512 blocks, 2/CU
    gemm_tile<128, 64, 4, 2, 0><<<dim3(16, 8, 4), 256, 0, stream>>>(
        MID, WT2, DOUTf, nullptr, ROWS, DMODEL, 512, FFN_DIM, FFN_DIM,
        0L, 0L, (long)SLAB, 0, 4, nullptr);
    if (layer < 5) {
      reduce_rms<<<ROWS, 128, 0, stream>>>(
          XBUF, DOUTf, ffn_b2 + layer * DMODEL, nssm_w + (layer + 1) * DMODEL,
          in_pe, in_mask, SBUF, nullptr);
    } else {
      reduce_rms<<<ROWS, 128, 0, stream>>>(
          XBUF, DOUTf, ffn_b2 + layer * DMODEL, final_w,
          nullptr, nullptr, nullptr, (float*)d_out);
    }
  }
}

// Round 15
// 971.946 us; speedup vs baseline: 1.0213x; 1.0213x over previous
//
#include <hip/hip_runtime.h>
#include <cstdint>
#include <cstddef>

typedef __bf16 bf16;
typedef __bf16 bf16x4 __attribute__((ext_vector_type(4)));
typedef __bf16 bf16x8 __attribute__((ext_vector_type(8)));
typedef float f32x4 __attribute__((ext_vector_type(4)));

#define L_SEQ   1024
#define DMODEL  512
#define DINNER  1024
#define DSTATE  16
#define NHEADS  16
#define HEADDIM 64
#define CONVDIM 1056
#define DINPROJ 2096
#define FFN_DIM 2048
#define ROWS    2048   // B*L
#define CHUNK   64
#define NCHUNK  16
#define SLAB    ((size_t)ROWS * DMODEL)

__device__ __forceinline__ float wave_sum(float v) {
#pragma unroll
  for (int off = 32; off; off >>= 1) v += __shfl_down(v, off, 64);
  return v;
}
__device__ __forceinline__ float silu_f(float x) { return x / (1.0f + expf(-x)); }

// ---------------- RMS norm (+pe/mask), bf16 out (used once, layer 0) -------
__global__ __launch_bounds__(128) void rms_kernel(
    const float* __restrict__ x, const float* __restrict__ w,
    const float* __restrict__ pe, const float* __restrict__ mask,
    bf16* __restrict__ outb)
{
  int r = blockIdx.x, t = threadIdx.x;
  float4 v = ((const float4*)(x + (size_t)r * DMODEL))[t];
  float ss = v.x*v.x + v.y*v.y + v.z*v.z + v.w*v.w;
  ss = wave_sum(ss);
  __shared__ float red[2];
  if ((t & 63) == 0) red[t >> 6] = ss;
  __syncthreads();
  float rs = 1.0f / sqrtf((red[0] + red[1]) * (1.0f / DMODEL) + 1e-6f);
  float4 wv = ((const float4*)w)[t];
  float4 p = ((const float4*)(pe + (size_t)r * DMODEL))[t];
  float m = mask[r];
  bf16x4 o;
  o[0] = (bf16)((v.x*rs*wv.x + p.x) * m);
  o[1] = (bf16)((v.y*rs*wv.y + p.y) * m);
  o[2] = (bf16)((v.z*rs*wv.z + p.z) * m);
  o[3] = (bf16)((v.w*rs*wv.w + p.w) * m);
  *(bf16x4*)&outb[(size_t)r * DMODEL + t * 4] = o;
}

// ------- transpose+cvt ALL weights, ONE dispatch (frozen: HBM-pattern-bound)
__global__ __launch_bounds__(256) void transpose_all(
    const float* __restrict__ W_in, const float* __restrict__ W_out,
    const float* __restrict__ f1, const float* __restrict__ f2,
    bf16* __restrict__ TIN, bf16* __restrict__ TOUT,
    bf16* __restrict__ T1, bf16* __restrict__ T2)
{
  int bid = blockIdx.x;
  const float* src; bf16* dst; int K, N, k0, n0;
  if (bid < 3168) {                  // W_in: 12 x (4 kt x 66 nt)
    int slice = bid / 264, rem = bid % 264;
    K = 512; N = 2096;
    k0 = (rem & 3) * 128; n0 = (rem >> 2) * 32;
    src = W_in + (size_t)slice * K * N;  dst = TIN + (size_t)slice * N * K;
  } else if (bid < 4704) {           // W_out: 12 x (8 kt x 16 nt)
    int t2 = bid - 3168;
    int slice = t2 / 128, rem = t2 % 128;
    K = 1024; N = 512;
    k0 = (rem & 7) * 128; n0 = (rem >> 3) * 32;
    src = W_out + (size_t)slice * K * N; dst = TOUT + (size_t)slice * N * K;
  } else if (bid < 6240) {           // ffn1: 6 x (4 kt x 64 nt)
    int t3 = bid - 4704;
    int slice = t3 / 256, rem = t3 % 256;
    K = 512; N = 2048;
    k0 = (rem & 3) * 128; n0 = (rem >> 2) * 32;
    src = f1 + (size_t)slice * K * N;    dst = T1 + (size_t)slice * N * K;
  } else {                           // ffn2: 6 x (16 kt x 16 nt)
    int t4 = bid - 6240;
    int slice = t4 / 256, rem = t4 % 256;
    K = 2048; N = 512;
    k0 = (rem & 15) * 128; n0 = (rem >> 4) * 32;
    src = f2 + (size_t)slice * K * N;    dst = T2 + (size_t)slice * N * K;
  }
  __shared__ float tile[128][33];
  int fq = threadIdx.x & 7, kr = threadIdx.x >> 3;
#pragma unroll
  for (int p = 0; p < 4; p++) {
    int k = kr + 32 * p;
    float4 v = {0.0f, 0.0f, 0.0f, 0.0f};
    int n = n0 + fq * 4;
    if (n < N) v = *(const float4*)&src[(size_t)(k0 + k) * N + n];
    int cq = (fq * 4) ^ (((k >> 3) & 7) << 2);   // swizzled quad base
    *(float4*)&tile[k][cq] = v;
  }
  __syncthreads();
  int kg = threadIdx.x & 15, nb = threadIdx.x >> 4;
#pragma unroll
  for (int p = 0; p < 2; p++) {
    int nn = nb + 16 * p;
    if (n0 + nn < N) {
      bf16x8 o;
#pragma unroll
      for (int j = 0; j < 8; j++) {
        int row = kg * 8 + j;
        o[j] = (bf16)tile[row][nn ^ (((row >> 3) & 7) << 2)];
      }
      *(bf16x8*)&dst[(size_t)(n0 + nn) * K + k0 + kg * 8] = o;
    }
  }
}

// ---------------- bf16 MFMA GEMM, BK=64 two-half LDS, gload_lds staging ----
// MODE 0: f32 out  MODE 1: +bias,gelu,bf16 out  MODE 3: bf16 out + f32 dt tail
// z axis = dir * kspl + ks
template<int BM, int BN, int FI, int FJ, int MODE>
__global__ __launch_bounds__(256) void gemm_tile(
    const bf16* __restrict__ A, const bf16* __restrict__ BT,
    float* __restrict__ Cf, bf16* __restrict__ Cb,
    int M, int N, int K, int lda, int ldb,
    long aOffz, long bOffz, long cOffz, int flipz, int kspl,
    const float* __restrict__ bias)
{
  constexpr int CH = (BM + BN) * 8;        // 16B chunks per 64-k step
  constexpr int NI = CH / 256;             // gload_lds per thread-group pass
  constexpr int HC = CH / 2;               // chunks per 32-k half
  constexpr int HALF = (BM + BN) * 32;     // bf16 elems per half buffer

  int z = blockIdx.z;
  int dir = z / kspl, ks = z - dir * kspl;
  A  += (size_t)dir * aOffz + (size_t)ks * K;
  BT += (size_t)dir * bOffz + (size_t)ks * K;
  long coff = (size_t)z * cOffz;
  int doflip = (flipz && dir == 1);

  __shared__ __align__(16) bf16 Tile[2 * HALF];

  int m0 = blockIdx.x * BM, n0 = blockIdx.y * BN;
  int t = threadIdx.x;
  int lane = t & 63, w = t >> 6;
  int wr = w >> 1, wc = w & 1;
  int lr = lane & 15, lq = lane >> 4;

  const bf16* gsrc[NI];
  int ldsoff[NI];
#pragma unroll
  for (int i = 0; i < NI; i++) {
    int g0 = w * (CH / 4) + i * 64;        // wave-uniform chunk base
    int g  = g0 + lane;
    int half = g / HC;                     // whole 64-chunk run same half
    int wi = g - half * HC;
    int row = wi >> 2, kp = wi & 3;
    int kcol = half * 32 + kp * 8;
    if (row < BM) {
      int gr = m0 + row;
      if (doflip) gr ^= (L_SEQ - 1);
      gsrc[i] = A + (size_t)gr * lda + kcol;
    } else {
      int gn = n0 + (row - BM); if (gn >= N) gn = N - 1;
      gsrc[i] = BT + (size_t)gn * ldb + kcol;
    }
    int half0 = g0 / HC, wi0 = g0 - half0 * HC;
    ldsoff[i] = half0 * HALF + wi0 * 8;
  }

  f32x4 zf = {0.0f, 0.0f, 0.0f, 0.0f};
  f32x4 acc[FI][FJ];
#pragma unroll
  for (int i = 0; i < FI; i++)
#pragma unroll
    for (int j = 0; j < FJ; j++) acc[i][j] = zf;

  for (int k0 = 0; k0 < K; k0 += 64) {
#pragma unroll
    for (int i = 0; i < NI; i++) {
      __builtin_amdgcn_global_load_lds(
          (const __attribute__((address_space(1))) void*)(gsrc[i] + k0),
          (__attribute__((address_space(3))) void*)&Tile[ldsoff[i]],
          16, 0, 0);
    }
    __syncthreads();

#pragma unroll
    for (int hf = 0; hf < 2; hf++) {
      const bf16* As = Tile + hf * HALF;
      const bf16* Bs = As + BM * 32;
      bf16x8 af[FI], bfv[FJ];
#pragma unroll
      for (int i = 0; i < FI; i++)
        af[i] = *(const bf16x8*)&As[(wr * 64 + i * 16 + lr) * 32 + lq * 8];
#pragma unroll
      for (int j = 0; j < FJ; j++)
        bfv[j] = *(const bf16x8*)&Bs[(wc * (BN / 2) + j * 16 + lr) * 32 + lq * 8];
#pragma unroll
      for (int i = 0; i < FI; i++)
#pragma unroll
        for (int j = 0; j < FJ; j++)
          acc[i][j] = __builtin_amdgcn_mfma_f32_16x16x32_bf16(af[i], bfv[j], acc[i][j], 0, 0, 0);
    }
    __syncthreads();
  }

#pragma unroll
  for (int i = 0; i < FI; i++) {
    int growb = m0 + wr * 64 + i * 16 + lq * 4;
#pragma unroll
    for (int j = 0; j < FJ; j++) {
      int gcol = n0 + wc * (BN / 2) + j * 16 + lr;
      if (gcol >= N) continue;
#pragma unroll
      for (int rr = 0; rr < 4; rr++) {
        int grow = growb + rr;
        float v = acc[i][j][rr];
        if (MODE == 1) {
          v += bias[gcol];
          v = 0.5f * v * (1.0f + erff(v * 0.70710678118f));
          Cb[coff + (size_t)grow * N + gcol] = (bf16)v;
        } else if (MODE == 3) {
          Cb[coff + (size_t)grow * N + gcol] = (bf16)v;
          if (gcol >= DINNER + CONVDIM)
            Cf[(size_t)z * ROWS * 16 + (size_t)grow * 16 + (gcol - (DINNER + CONVDIM))] = v;
        } else {
          Cf[coff + (size_t)grow * N + gcol] = v;
        }
      }
    }
  }
}

// ------ conv+silu for the 32 B/C channels only (compact f32 out) + dt/dA ----
__global__ __launch_bounds__(64) void convdt_bc(
    const bf16* __restrict__ ZX, const float* __restrict__ DTRAW,
    float* __restrict__ BCf, float* __restrict__ DT, float* __restrict__ DA,
    const float* __restrict__ conv_w, const float* __restrict__ conv_b,
    const float* __restrict__ dt_bias, const float* __restrict__ A_log)
{
  int r = blockIdx.x, dir = blockIdx.y;
  int l = r & (L_SEQ - 1);
  int t = threadIdx.x;
  if (t < 32) {
    int ch = DINNER + t;             // conv channel 1024+t (B/C block)
    const float* cw = conv_w + ((size_t)dir * CONVDIM + ch) * 4;
    float acc = conv_b[(size_t)dir * CONVDIM + ch];
    const bf16* zc = ZX + (size_t)dir * ROWS * DINPROJ + DINNER + ch;
#pragma unroll
    for (int k = 0; k < 4; k++) {
      int ls = l + k - 3;
      if (ls >= 0) acc += (float)zc[(size_t)(r + k - 3) * DINPROJ] * cw[k];
    }
    BCf[((size_t)dir * ROWS + r) * 32 + t] = silu_f(acc);
  } else if (t < 48) {
    int h = t - 32;
    float raw = DTRAW[((size_t)dir * ROWS + r) * 16 + h] + dt_bias[dir * NHEADS + h];
    float dt = (raw > 20.0f) ? raw : log1pf(expf(raw));
    float A = -expf(A_log[dir * NHEADS + h]);
    size_t idx = ((size_t)dir * ROWS + r) * NHEADS + h;
    DT[idx] = dt;
    DA[idx] = expf(dt * A);
  }
}

// ---- chunked SSM scan pass 1: inline x-conv (sliding window) + local scan,
//      writes y + D*x (bf16). One wave per (dir,b,head,chunk). ----
__global__ __launch_bounds__(64) void scan1_kernel(
    const bf16* __restrict__ ZX, const float* __restrict__ BCf,
    const float* __restrict__ DT, const float* __restrict__ DA,
    bf16* __restrict__ YSSM, float* __restrict__ HEND,
    float* __restrict__ APROD,
    const float* __restrict__ conv_w, const float* __restrict__ conv_b,
    const float* __restrict__ Dparam)
{
  int bid = blockIdx.x;
  int g = bid >> 4, c = bid & 15;
  int dir = g >> 5, rem = g & 31;
  int b = rem >> 4, h = rem & 15;
  int lane = threadIdx.x;
  size_t rowbase = (size_t)dir * ROWS + b * L_SEQ + c * CHUNK;

  float dtv = DT[(rowbase + lane) * NHEADS + h];
  float dav = DA[(rowbase + lane) * NHEADS + h];

  float ap = dav;
#pragma unroll
  for (int off = 1; off < 64; off <<= 1) {
    float o = __shfl_up(ap, off, 64);
    if (lane >= off) ap *= o;
  }
  APROD[((size_t)g * NCHUNK + c) * 64 + lane] = ap;

  // stage conv'd B|C (32 f32/row) into LDS
  __shared__ float BCs[CHUNK][36];
#pragma unroll
  for (int i = 0; i < 8; i++) {
    int l = i * 8 + (lane >> 3), f = lane & 7;
    float4 v = *(const float4*)&BCf[(rowbase + l) * 32 + f * 4];
    *(float4*)&BCs[l][f * 4] = v;
  }
  __syncthreads();

  // x-conv setup: lane owns channel ch = h*64+lane; sliding 4-tap window
  int ch = h * HEADDIM + lane;
  f32x4 cwv = *(const f32x4*)&conv_w[((size_t)dir * CONVDIM + ch) * 4];
  float cbv = conv_b[(size_t)dir * CONVDIM + ch];
  const bf16* xcol = ZX + rowbase * DINPROJ + DINNER + ch;  // stride DINPROJ
  int lg0 = c * CHUNK;   // global seq pos of chunk start
  float xm3 = (lg0 >= 3) ? (float)xcol[-3 * DINPROJ] : 0.0f;
  float xm2 = (lg0 >= 2) ? (float)xcol[-2 * DINPROJ] : 0.0f;
  float xm1 = (lg0 >= 1) ? (float)xcol[-1 * DINPROJ] : 0.0f;

  float Dv = Dparam[dir * NHEADS + h];

  float hs[16];
#pragma unroll
  for (int n = 0; n < 16; n++) hs[n] = 0.0f;

  bf16* yp = YSSM + rowbase * DINNER + ch;

#pragma unroll 4
  for (int l = 0; l < CHUNK; l++) {
    float dt = __shfl(dtv, l, 64);
    float da = __shfl(dav, l, 64);
    float xcur = (float)xcol[(size_t)l * DINPROJ];
    float conv = cbv + cwv[0]*xm3 + cwv[1]*xm2 + cwv[2]*xm1 + cwv[3]*xcur;
    xm3 = xm2; xm2 = xm1; xm1 = xcur;
    float xv = silu_f(conv);
    float4 bq[4], cq[4];
#pragma unroll
    for (int q = 0; q < 4; q++) {
      bq[q] = *(const float4*)&BCs[l][q * 4];
      cq[q] = *(const float4*)&BCs[l][16 + q * 4];
    }
    const float* Bv = (const float*)bq;
    const float* Cv = (const float*)cq;
    float dtx = dt * xv;
    float acc = 0.0f;
#pragma unroll
    for (int n = 0; n < 16; n++) {
      hs[n] = hs[n] * da + dtx * Bv[n];
      acc += hs[n] * Cv[n];
    }
    yp[(size_t)l * DINNER] = (bf16)(acc + Dv * xv);
  }

  float* he = HEND + ((size_t)g * NCHUNK + c) * 16 * 64;
#pragma unroll
  for (int n = 0; n < 16; n++) he[n * 64 + lane] = hs[n];
}

// ---- scan mid: chunk-level prefix of h-states (makes scan2 O(1)) ----
// hstart[c] = A_{c-1} * hstart[c-1] + hend[c-1]; A = APROD[chunk][63].
// One wave per g (64 blocks); lane owns state column.
__global__ __launch_bounds__(64) void scan_mid(
    const float* __restrict__ HEND, const float* __restrict__ APROD,
    float* __restrict__ HSTART)
{
  int g = blockIdx.x;
  int lane = threadIdx.x;
  float hst[16];
#pragma unroll
  for (int n = 0; n < 16; n++) hst[n] = 0.0f;
  for (int c = 1; c < NCHUNK; c++) {
    const float* he = HEND + ((size_t)g * NCHUNK + (c - 1)) * 16 * 64;
    float w = APROD[((size_t)g * NCHUNK + (c - 1)) * 64 + 63];
    float* ho = HSTART + ((size_t)g * NCHUNK + c) * 16 * 64;
#pragma unroll
    for (int n = 0; n < 16; n++) {
      hst[n] = hst[n] * w + he[n * 64 + lane];
      ho[n * 64 + lane] = hst[n];
    }
  }
}

// ---------------- chunked SSM scan, pass 2: apply precomputed hstart ------
__global__ __launch_bounds__(64) void scan2_kernel(
    const float* __restrict__ BCf, bf16* __restrict__ YSSM,
    const float* __restrict__ HSTART, const float* __restrict__ APROD)
{
  int bid = blockIdx.x;
  int g = bid >> 4, c = bid & 15;
  if (c == 0) return;
  int dir = g >> 5, rem = g & 31;
  int b = rem >> 4, h = rem & 15;
  int lane = threadIdx.x;

  float hstart[16];
  const float* hi = HSTART + ((size_t)g * NCHUNK + c) * 16 * 64;
#pragma unroll
  for (int n = 0; n < 16; n++) hstart[n] = hi[n * 64 + lane];

  size_t rowbase = (size_t)dir * ROWS + b * L_SEQ + c * CHUNK;
  bf16* yp = YSSM + rowbase * DINNER + h * HEADDIM + lane;
  float apv = APROD[((size_t)g * NCHUNK + c) * 64 + lane];

  __shared__ float Cs[CHUNK][20];
#pragma unroll
  for (int i = 0; i < 4; i++) {
    int l = i * 16 + (lane >> 2), f = lane & 3;
    float4 v = *(const float4*)&BCf[(rowbase + l) * 32 + 16 + f * 4];
    *(float4*)&Cs[l][f * 4] = v;
  }
  __syncthreads();

#pragma unroll 4
  for (int l = 0; l < CHUNK; l++) {
    float a = __shfl(apv, l, 64);
    float4 cq[4];
#pragma unroll
    for (int q = 0; q < 4; q++) cq[q] = *(const float4*)&Cs[l][q * 4];
    const float* Cv = (const float*)cq;
    float acc = 0.0f;
#pragma unroll
    for (int n = 0; n < 16; n++) acc += Cv[n] * hstart[n];
    float y = (float)yp[(size_t)l * DINNER];
    yp[(size_t)l * DINNER] = (bf16)(y + a * acc);
  }
}

// ------- gate (y already has D*x): y*silu(z) + RMS(1024), bf16 out -------
__global__ __launch_bounds__(256) void gatenorm_kernel(
    const bf16* __restrict__ YSSM, const bf16* __restrict__ ZX,
    const float* __restrict__ mnorm_w, bf16* __restrict__ YB)
{
  int r = blockIdx.x, dir = blockIdx.y, t = threadIdx.x;
  const bf16* y = YSSM + ((size_t)dir * ROWS + r) * DINNER;
  const bf16* z  = ZX  + ((size_t)dir * ROWS + r) * DINPROJ;
  int c = t * 4;
  bf16x4 yv4 = *(const bf16x4*)&y[c];
  bf16x4 zv4 = *(const bf16x4*)&z[c];
  float val[4];
#pragma unroll
  for (int q = 0; q < 4; q++)
    val[q] = (float)yv4[q] * silu_f((float)zv4[q]);
  float ss = val[0]*val[0] + val[1]*val[1] + val[2]*val[2] + val[3]*val[3];
  ss = wave_sum(ss);
  __shared__ float red[4];
  if ((t & 63) == 0) red[t >> 6] = ss;
  __syncthreads();
  float total = red[0] + red[1] + red[2] + red[3];
  float rs = 1.0f / sqrtf(total * (1.0f / DINNER) + 1e-5f);
  float4 wv = *(const float4*)&mnorm_w[dir * DINNER + c];
  bf16x4 o;
  o[0] = (bf16)(val[0] * rs * wv.x);
  o[1] = (bf16)(val[1] * rs * wv.y);
  o[2] = (bf16)(val[2] * rs * wv.z);
  o[3] = (bf16)(val[3] * rs * wv.w);
  *(bf16x4*)&YB[((size_t)dir * ROWS + r) * DINNER + c] = o;
}

// ------ combine (x += 0.5*(f+flip(b))*mask) + FFN RMS, bf16 out ------
__global__ __launch_bounds__(128) void combine_rms(
    const float* __restrict__ Xsrc, float* __restrict__ X,
    const float* __restrict__ P, const float* __restrict__ mask,
    const float* __restrict__ w, bf16* __restrict__ outb)
{
  int r = blockIdx.x, t = threadIdx.x;
  int b = r >> 10, l = r & 1023;
  int c = t * 4;
  float m = 0.5f * mask[r];
  float4 f0 = *(const float4*)&P[(size_t)r * DMODEL + c];
  float4 f1 = *(const float4*)&P[SLAB + (size_t)r * DMODEL + c];
  size_t fr = (size_t)(b * L_SEQ + (L_SEQ - 1 - l)) * DMODEL + c;
  float4 b0 = *(const float4*)&P[2 * SLAB + fr];
  float4 b1 = *(const float4*)&P[3 * SLAB + fr];
  float4 x = *(const float4*)&Xsrc[(size_t)r * DMODEL + c];
  x.x += m * (f0.x + f1.x + b0.x + b1.x);
  x.y += m * (f0.y + f1.y + b0.y + b1.y);
  x.z += m * (f0.z + f1.z + b0.z + b1.z);
  x.w += m * (f0.w + f1.w + b0.w + b1.w);
  *(float4*)&X[(size_t)r * DMODEL + c] = x;
  float ss = x.x*x.x + x.y*x.y + x.z*x.z + x.w*x.w;
  ss = wave_sum(ss);
  __shared__ float red[2];
  if ((t & 63) == 0) red[t >> 6] = ss;
  __syncthreads();
  float rs = 1.0f / sqrtf((red[0] + red[1]) * (1.0f / DMODEL) + 1e-6f);
  float4 wv = *(const float4*)&w[c];
  bf16x4 o;
  o[0] = (bf16)(x.x * rs * wv.x);
  o[1] = (bf16)(x.y * rs * wv.y);
  o[2] = (bf16)(x.z * rs * wv.z);
  o[3] = (bf16)(x.w * rs * wv.w);
  *(bf16x4*)&outb[(size_t)r * DMODEL + c] = o;
}

// ------ FFN2 splitK reduce (4 slabs) + bias + resid, then RMS ---
__global__ __launch_bounds__(128) void reduce_rms(
    float* __restrict__ X, const float* __restrict__ P,
    const float* __restrict__ bias, const float* __restrict__ w,
    const float* __restrict__ pe, const float* __restrict__ mask,
    bf16* __restrict__ outb, float* __restrict__ outf)
{
  int r = blockIdx.x, t = threadIdx.x;
  int c = t * 4;
  size_t off = (size_t)r * DMODEL + c;
  float4 a0 = *(const float4*)&P[off];
  float4 a1 = *(const float4*)&P[SLAB + off];
  float4 a2 = *(const float4*)&P[2 * SLAB + off];
  float4 a3 = *(const float4*)&P[3 * SLAB + off];
  float4 bi = *(const float4*)&bias[c];
  float4 x  = *(float4*)&X[off];
  x.x += a0.x + a1.x + a2.x + a3.x + bi.x;
  x.y += a0.y + a1.y + a2.y + a3.y + bi.y;
  x.z += a0.z + a1.z + a2.z + a3.z + bi.z;
  x.w += a0.w + a1.w + a2.w + a3.w + bi.w;
  *(float4*)&X[off] = x;
  float ss = x.x*x.x + x.y*x.y + x.z*x.z + x.w*x.w;
  ss = wave_sum(ss);
  __shared__ float red[2];
  if ((t & 63) == 0) red[t >> 6] = ss;
  __syncthreads();
  float rs = 1.0f / sqrtf((red[0] + red[1]) * (1.0f / DMODEL) + 1e-6f);
  float4 wv = *(const float4*)&w[c];
  float4 o;
  o.x = x.x*rs*wv.x; o.y = x.y*rs*wv.y; o.z = x.z*rs*wv.z; o.w = x.w*rs*wv.w;
  if (pe) {
    float4 p = *(const float4*)&pe[off];
    float m = mask[r];
    o.x = (o.x + p.x)*m; o.y = (o.y + p.y)*m; o.z = (o.z + p.z)*m; o.w = (o.w + p.w)*m;
  }
  if (outb) {
    bf16x4 ob = {(bf16)o.x, (bf16)o.y, (bf16)o.z, (bf16)o.w};
    *(bf16x4*)&outb[off] = ob;
  } else {
    *(float4*)&outf[off] = o;
  }
}

// ---------------- host ----------------
extern "C" void kernel_launch(void* const* d_in, const int* in_sizes, int n_in,
                              void* d_out, int out_size, void* d_ws, size_t ws_size,
                              hipStream_t stream)
{
  const float* in_x    = (const float*)d_in[0];
  const float* in_pe   = (const float*)d_in[1];
  const float* in_mask = (const float*)d_in[2];
  const float* W_in    = (const float*)d_in[3];
  const float* conv_w  = (const float*)d_in[4];
  const float* conv_b  = (const float*)d_in[5];
  const float* A_log   = (const float*)d_in[6];
  const float* Dparam  = (const float*)d_in[7];
  const float* dt_bias = (const float*)d_in[8];
  const float* mnorm_w = (const float*)d_in[9];
  const float* W_out   = (const float*)d_in[10];
  const float* nssm_w  = (const float*)d_in[11];
  const float* ffn_w1  = (const float*)d_in[12];
  const float* ffn_b1  = (const float*)d_in[13];
  const float* ffn_w2  = (const float*)d_in[14];
  const float* ffn_b2  = (const float*)d_in[15];
  const float* nffn_w  = (const float*)d_in[16];
  const float* final_w = (const float*)d_in[17];

  if (ws_size < 126287872) return;

  // workspace layout. DOUT (4 f32 slabs, 16.78MB) OVERLAYS ZXb (verified).
  // HSTART (4MB) sits after APROD: 54,394,880 .. 58,589,184 < 62,783,488.
  char* ws = (char*)d_ws;
  float* XBUF  = (float*)(ws + 0);            //  4,194,304
  bf16*  SBUF  = (bf16*) (ws + 4194304);      //  2,097,152
  bf16*  ZXb   = (bf16*) (ws + 6291456);      // 17,170,432
  float* DOUTf = (float*)(ws + 6291456);      // 16,777,216 (alias of ZXb)
  float* DTRAW = (float*)(ws + 23461888);     //    262,144
  float* BCf   = (float*)(ws + 23724032);     //    524,288
  float* DTb   = (float*)(ws + 24248320);     //    262,144
  float* DAb   = (float*)(ws + 24510464);     //    262,144
  bf16*  YSSMb = (bf16*) (ws + 24772608);     //  8,388,608
  bf16*  YB    = (bf16*) (ws + 33161216);     //  8,388,608
  bf16*  MID   = (bf16*) (ws + 41549824);     //  8,388,608
  float* HEND  = (float*)(ws + 49938432);     //  4,194,304 -> 54,132,736
  float* APROD = (float*)(ws + 54132736);     //    262,144 -> 54,394,880
  float* HSTART= (float*)(ws + 54394880);     //  4,194,304 -> 58,589,184
  bf16*  WTINa = (bf16*) (ws + 62783488);     // 25,755,648
  bf16*  WTOUTa= (bf16*) (ws + 88539136);     // 12,582,912
  bf16*  WT1a  = (bf16*) (ws + 101122048);    // 12,582,912
  bf16*  WT2a  = (bf16*) (ws + 113704960);    // 12,582,912 -> 126,287,872

  transpose_all<<<7776, 256, 0, stream>>>(W_in, W_out, ffn_w1, ffn_w2,
                                          WTINa, WTOUTa, WT1a, WT2a);
  rms_kernel<<<ROWS, 128, 0, stream>>>(in_x, nssm_w, in_pe, in_mask, SBUF);

  for (int layer = 0; layer < 6; layer++) {
    const bf16* WTIN  = WTINa  + (size_t)layer * 2 * DMODEL * DINPROJ;
    const bf16* WTOUT = WTOUTa + (size_t)layer * 2 * DINNER * DMODEL;
    const bf16* WT1   = WT1a   + (size_t)layer * DMODEL * FFN_DIM;
    const bf16* WT2   = WT2a   + (size_t)layer * FFN_DIM * DMODEL;
    const float* cw_l = conv_w + (size_t)layer * 2 * CONVDIM * 4;
    const float* cb_l = conv_b + (size_t)layer * 2 * CONVDIM;

    gemm_tile<128, 128, 4, 4, 3><<<dim3(16, 17, 2), 256, 0, stream>>>(
        SBUF, WTIN, DTRAW, ZXb, ROWS, DINPROJ, DMODEL, DMODEL, DMODEL,
        0L, (long)DINPROJ * DMODEL, (long)ROWS * DINPROJ, 1, 1, nullptr);
    convdt_bc<<<dim3(ROWS, 2), 64, 0, stream>>>(
        ZXb, DTRAW, BCf, DTb, DAb, cw_l, cb_l,
        dt_bias + layer * 2 * NHEADS, A_log + layer * 2 * NHEADS);
    scan1_kernel<<<1024, 64, 0, stream>>>(
        ZXb, BCf, DTb, DAb, YSSMb, HEND, APROD, cw_l, cb_l,
        Dparam + layer * 2 * NHEADS);
    scan_mid<<<64, 64, 0, stream>>>(HEND, APROD, HSTART);
    scan2_kernel<<<1024, 64, 0, stream>>>(BCf, YSSMb, HSTART, APROD);
    gatenorm_kernel<<<dim3(ROWS, 2), 256, 0, stream>>>(
        YSSMb, ZXb, mnorm_w + layer * 2 * DINNER, YB);
    // W_out: z = dir*2 + ks (kspl=2, K=512 each) -> 512 blocks, 2/CU
    gemm_tile<128, 64, 4, 2, 0><<<dim3(16, 8, 4), 256, 0, stream>>>(
        YB, WTOUT, DOUTf, nullptr, ROWS, DMODEL, 512, DINNER, DINNER,
        (long)ROWS * DINNER, (long)DMODEL * DINNER, (long)SLAB, 0, 2, nullptr);
    combine_rms<<<ROWS, 128, 0, stream>>>(
        layer == 0 ? in_x : XBUF, XBUF, DOUTf, in_mask, nffn_w + layer * DMODEL, SBUF);

    // FFN
    gemm_tile<128, 64, 4, 2, 1><<<dim3(16, 32, 1), 256, 0, stream>>>(
        SBUF, WT1, nullptr, MID, ROWS, FFN_DIM, DMODEL, DMODEL, DMODEL,
        0L, 0L, 0L, 0, 1, ffn_b1 + layer * FFN_DIM);
    // FFN2: kspl=4 (K=512 each) -> 512 blocks, 2/CU
    gemm_tile<128, 64, 4, 2, 0><<<dim3(16, 8, 4), 256, 0, stream>>>(
        MID, WT2, DOUTf, nullptr, ROWS, DMODEL, 512, FFN_DIM, FFN_DIM,
        0L, 0L, (long)SLAB, 0, 4, nullptr);
    if (layer < 5) {
      reduce_rms<<<ROWS, 128, 0, stream>>>(
          XBUF, DOUTf, ffn_b2 + layer * DMODEL, nssm_w + (layer + 1) * DMODEL,
          in_pe, in_mask, SBUF, nullptr);
    } else {
      reduce_rms<<<ROWS, 128, 0, stream>>>(
          XBUF, DOUTf, ffn_b2 + layer * DMODEL, final_w,
          nullptr, nullptr, nullptr, (float*)d_out);
    }
  }
}

// Round 16
// 948.308 us; speedup vs baseline: 1.0467x; 1.0249x over previous
//
#include <hip/hip_runtime.h>
#include <cstdint>
#include <cstddef>

typedef __bf16 bf16;
typedef __bf16 bf16x4 __attribute__((ext_vector_type(4)));
typedef __bf16 bf16x8 __attribute__((ext_vector_type(8)));
typedef float f32x4 __attribute__((ext_vector_type(4)));

#define L_SEQ   1024
#define DMODEL  512
#define DINNER  1024
#define DSTATE  16
#define NHEADS  16
#define HEADDIM 64
#define CONVDIM 1056
#define DINPROJ 2096
#define FFN_DIM 2048
#define ROWS    2048   // B*L
#define CHUNK   64
#define NCHUNK  16
#define SLAB    ((size_t)ROWS * DMODEL)

__device__ __forceinline__ float wave_sum(float v) {
#pragma unroll
  for (int off = 32; off; off >>= 1) v += __shfl_down(v, off, 64);
  return v;
}
__device__ __forceinline__ float silu_f(float x) { return x / (1.0f + expf(-x)); }

// ---------------- RMS norm (+pe/mask), bf16 out (used once, layer 0) -------
__global__ __launch_bounds__(128) void rms_kernel(
    const float* __restrict__ x, const float* __restrict__ w,
    const float* __restrict__ pe, const float* __restrict__ mask,
    bf16* __restrict__ outb)
{
  int r = blockIdx.x, t = threadIdx.x;
  float4 v = ((const float4*)(x + (size_t)r * DMODEL))[t];
  float ss = v.x*v.x + v.y*v.y + v.z*v.z + v.w*v.w;
  ss = wave_sum(ss);
  __shared__ float red[2];
  if ((t & 63) == 0) red[t >> 6] = ss;
  __syncthreads();
  float rs = 1.0f / sqrtf((red[0] + red[1]) * (1.0f / DMODEL) + 1e-6f);
  float4 wv = ((const float4*)w)[t];
  float4 p = ((const float4*)(pe + (size_t)r * DMODEL))[t];
  float m = mask[r];
  bf16x4 o;
  o[0] = (bf16)((v.x*rs*wv.x + p.x) * m);
  o[1] = (bf16)((v.y*rs*wv.y + p.y) * m);
  o[2] = (bf16)((v.z*rs*wv.z + p.z) * m);
  o[3] = (bf16)((v.w*rs*wv.w + p.w) * m);
  *(bf16x4*)&outb[(size_t)r * DMODEL + t * 4] = o;
}

// ------- transpose+cvt ALL weights, ONE dispatch (frozen: HBM-pattern-bound)
__global__ __launch_bounds__(256) void transpose_all(
    const float* __restrict__ W_in, const float* __restrict__ W_out,
    const float* __restrict__ f1, const float* __restrict__ f2,
    bf16* __restrict__ TIN, bf16* __restrict__ TOUT,
    bf16* __restrict__ T1, bf16* __restrict__ T2)
{
  int bid = blockIdx.x;
  const float* src; bf16* dst; int K, N, k0, n0;
  if (bid < 3168) {                  // W_in: 12 x (4 kt x 66 nt)
    int slice = bid / 264, rem = bid % 264;
    K = 512; N = 2096;
    k0 = (rem & 3) * 128; n0 = (rem >> 2) * 32;
    src = W_in + (size_t)slice * K * N;  dst = TIN + (size_t)slice * N * K;
  } else if (bid < 4704) {           // W_out: 12 x (8 kt x 16 nt)
    int t2 = bid - 3168;
    int slice = t2 / 128, rem = t2 % 128;
    K = 1024; N = 512;
    k0 = (rem & 7) * 128; n0 = (rem >> 3) * 32;
    src = W_out + (size_t)slice * K * N; dst = TOUT + (size_t)slice * N * K;
  } else if (bid < 6240) {           // ffn1: 6 x (4 kt x 64 nt)
    int t3 = bid - 4704;
    int slice = t3 / 256, rem = t3 % 256;
    K = 512; N = 2048;
    k0 = (rem & 3) * 128; n0 = (rem >> 2) * 32;
    src = f1 + (size_t)slice * K * N;    dst = T1 + (size_t)slice * N * K;
  } else {                           // ffn2: 6 x (16 kt x 16 nt)
    int t4 = bid - 6240;
    int slice = t4 / 256, rem = t4 % 256;
    K = 2048; N = 512;
    k0 = (rem & 15) * 128; n0 = (rem >> 4) * 32;
    src = f2 + (size_t)slice * K * N;    dst = T2 + (size_t)slice * N * K;
  }
  __shared__ float tile[128][33];
  int fq = threadIdx.x & 7, kr = threadIdx.x >> 3;
#pragma unroll
  for (int p = 0; p < 4; p++) {
    int k = kr + 32 * p;
    float4 v = {0.0f, 0.0f, 0.0f, 0.0f};
    int n = n0 + fq * 4;
    if (n < N) v = *(const float4*)&src[(size_t)(k0 + k) * N + n];
    int cq = (fq * 4) ^ (((k >> 3) & 7) << 2);   // swizzled quad base
    *(float4*)&tile[k][cq] = v;
  }
  __syncthreads();
  int kg = threadIdx.x & 15, nb = threadIdx.x >> 4;
#pragma unroll
  for (int p = 0; p < 2; p++) {
    int nn = nb + 16 * p;
    if (n0 + nn < N) {
      bf16x8 o;
#pragma unroll
      for (int j = 0; j < 8; j++) {
        int row = kg * 8 + j;
        o[j] = (bf16)tile[row][nn ^ (((row >> 3) & 7) << 2)];
      }
      *(bf16x8*)&dst[(size_t)(n0 + nn) * K + k0 + kg * 8] = o;
    }
  }
}

// ---------------- bf16 MFMA GEMM, BK=64 two-half LDS, gload_lds staging ----
// MODE 0: f32 out  MODE 1: +bias,gelu,bf16 out  MODE 3: bf16 out + f32 dt tail
// z axis = dir * kspl + ks
template<int BM, int BN, int FI, int FJ, int MODE>
__global__ __launch_bounds__(256) void gemm_tile(
    const bf16* __restrict__ A, const bf16* __restrict__ BT,
    float* __restrict__ Cf, bf16* __restrict__ Cb,
    int M, int N, int K, int lda, int ldb,
    long aOffz, long bOffz, long cOffz, int flipz, int kspl,
    const float* __restrict__ bias)
{
  constexpr int CH = (BM + BN) * 8;        // 16B chunks per 64-k step
  constexpr int NI = CH / 256;             // gload_lds per thread-group pass
  constexpr int HC = CH / 2;               // chunks per 32-k half
  constexpr int HALF = (BM + BN) * 32;     // bf16 elems per half buffer

  int z = blockIdx.z;
  int dir = z / kspl, ks = z - dir * kspl;
  A  += (size_t)dir * aOffz + (size_t)ks * K;
  BT += (size_t)dir * bOffz + (size_t)ks * K;
  long coff = (size_t)z * cOffz;
  int doflip = (flipz && dir == 1);

  __shared__ __align__(16) bf16 Tile[2 * HALF];

  int m0 = blockIdx.x * BM, n0 = blockIdx.y * BN;
  int t = threadIdx.x;
  int lane = t & 63, w = t >> 6;
  int wr = w >> 1, wc = w & 1;
  int lr = lane & 15, lq = lane >> 4;

  const bf16* gsrc[NI];
  int ldsoff[NI];
#pragma unroll
  for (int i = 0; i < NI; i++) {
    int g0 = w * (CH / 4) + i * 64;        // wave-uniform chunk base
    int g  = g0 + lane;
    int half = g / HC;                     // whole 64-chunk run same half
    int wi = g - half * HC;
    int row = wi >> 2, kp = wi & 3;
    int kcol = half * 32 + kp * 8;
    if (row < BM) {
      int gr = m0 + row;
      if (doflip) gr ^= (L_SEQ - 1);
      gsrc[i] = A + (size_t)gr * lda + kcol;
    } else {
      int gn = n0 + (row - BM); if (gn >= N) gn = N - 1;
      gsrc[i] = BT + (size_t)gn * ldb + kcol;
    }
    int half0 = g0 / HC, wi0 = g0 - half0 * HC;
    ldsoff[i] = half0 * HALF + wi0 * 8;
  }

  f32x4 zf = {0.0f, 0.0f, 0.0f, 0.0f};
  f32x4 acc[FI][FJ];
#pragma unroll
  for (int i = 0; i < FI; i++)
#pragma unroll
    for (int j = 0; j < FJ; j++) acc[i][j] = zf;

  for (int k0 = 0; k0 < K; k0 += 64) {
#pragma unroll
    for (int i = 0; i < NI; i++) {
      __builtin_amdgcn_global_load_lds(
          (const __attribute__((address_space(1))) void*)(gsrc[i] + k0),
          (__attribute__((address_space(3))) void*)&Tile[ldsoff[i]],
          16, 0, 0);
    }
    __syncthreads();

#pragma unroll
    for (int hf = 0; hf < 2; hf++) {
      const bf16* As = Tile + hf * HALF;
      const bf16* Bs = As + BM * 32;
      bf16x8 af[FI], bfv[FJ];
#pragma unroll
      for (int i = 0; i < FI; i++)
        af[i] = *(const bf16x8*)&As[(wr * 64 + i * 16 + lr) * 32 + lq * 8];
#pragma unroll
      for (int j = 0; j < FJ; j++)
        bfv[j] = *(const bf16x8*)&Bs[(wc * (BN / 2) + j * 16 + lr) * 32 + lq * 8];
#pragma unroll
      for (int i = 0; i < FI; i++)
#pragma unroll
        for (int j = 0; j < FJ; j++)
          acc[i][j] = __builtin_amdgcn_mfma_f32_16x16x32_bf16(af[i], bfv[j], acc[i][j], 0, 0, 0);
    }
    __syncthreads();
  }

#pragma unroll
  for (int i = 0; i < FI; i++) {
    int growb = m0 + wr * 64 + i * 16 + lq * 4;
#pragma unroll
    for (int j = 0; j < FJ; j++) {
      int gcol = n0 + wc * (BN / 2) + j * 16 + lr;
      if (gcol >= N) continue;
#pragma unroll
      for (int rr = 0; rr < 4; rr++) {
        int grow = growb + rr;
        float v = acc[i][j][rr];
        if (MODE == 1) {
          v += bias[gcol];
          v = 0.5f * v * (1.0f + erff(v * 0.70710678118f));
          Cb[coff + (size_t)grow * N + gcol] = (bf16)v;
        } else if (MODE == 3) {
          Cb[coff + (size_t)grow * N + gcol] = (bf16)v;
          if (gcol >= DINNER + CONVDIM)
            Cf[(size_t)z * ROWS * 16 + (size_t)grow * 16 + (gcol - (DINNER + CONVDIM))] = v;
        } else {
          Cf[coff + (size_t)grow * N + gcol] = v;
        }
      }
    }
  }
}

// ------ conv+silu for the 32 B/C channels only (compact f32 out) + dt/dA ----
__global__ __launch_bounds__(64) void convdt_bc(
    const bf16* __restrict__ ZX, const float* __restrict__ DTRAW,
    float* __restrict__ BCf, float* __restrict__ DT, float* __restrict__ DA,
    const float* __restrict__ conv_w, const float* __restrict__ conv_b,
    const float* __restrict__ dt_bias, const float* __restrict__ A_log)
{
  int r = blockIdx.x, dir = blockIdx.y;
  int l = r & (L_SEQ - 1);
  int t = threadIdx.x;
  if (t < 32) {
    int ch = DINNER + t;             // conv channel 1024+t (B/C block)
    const float* cw = conv_w + ((size_t)dir * CONVDIM + ch) * 4;
    float acc = conv_b[(size_t)dir * CONVDIM + ch];
    const bf16* zc = ZX + (size_t)dir * ROWS * DINPROJ + DINNER + ch;
#pragma unroll
    for (int k = 0; k < 4; k++) {
      int ls = l + k - 3;
      if (ls >= 0) acc += (float)zc[(size_t)(r + k - 3) * DINPROJ] * cw[k];
    }
    BCf[((size_t)dir * ROWS + r) * 32 + t] = silu_f(acc);
  } else if (t < 48) {
    int h = t - 32;
    float raw = DTRAW[((size_t)dir * ROWS + r) * 16 + h] + dt_bias[dir * NHEADS + h];
    float dt = (raw > 20.0f) ? raw : log1pf(expf(raw));
    float A = -expf(A_log[dir * NHEADS + h]);
    size_t idx = ((size_t)dir * ROWS + r) * NHEADS + h;
    DT[idx] = dt;
    DA[idx] = expf(dt * A);
  }
}

// ---- chunked SSM scan pass 1: inline x-conv (sliding window) + local scan,
//      writes y + D*x (bf16). One wave per (dir,b,head,chunk). ----
__global__ __launch_bounds__(64) void scan1_kernel(
    const bf16* __restrict__ ZX, const float* __restrict__ BCf,
    const float* __restrict__ DT, const float* __restrict__ DA,
    bf16* __restrict__ YSSM, float* __restrict__ HEND,
    float* __restrict__ APROD,
    const float* __restrict__ conv_w, const float* __restrict__ conv_b,
    const float* __restrict__ Dparam)
{
  int bid = blockIdx.x;
  int g = bid >> 4, c = bid & 15;
  int dir = g >> 5, rem = g & 31;
  int b = rem >> 4, h = rem & 15;
  int lane = threadIdx.x;
  size_t rowbase = (size_t)dir * ROWS + b * L_SEQ + c * CHUNK;

  float dtv = DT[(rowbase + lane) * NHEADS + h];
  float dav = DA[(rowbase + lane) * NHEADS + h];

  float ap = dav;
#pragma unroll
  for (int off = 1; off < 64; off <<= 1) {
    float o = __shfl_up(ap, off, 64);
    if (lane >= off) ap *= o;
  }
  APROD[((size_t)g * NCHUNK + c) * 64 + lane] = ap;

  // stage conv'd B|C (32 f32/row) into LDS
  __shared__ float BCs[CHUNK][36];
#pragma unroll
  for (int i = 0; i < 8; i++) {
    int l = i * 8 + (lane >> 3), f = lane & 7;
    float4 v = *(const float4*)&BCf[(rowbase + l) * 32 + f * 4];
    *(float4*)&BCs[l][f * 4] = v;
  }
  __syncthreads();

  // x-conv setup: lane owns channel ch = h*64+lane; sliding 4-tap window
  int ch = h * HEADDIM + lane;
  f32x4 cwv = *(const f32x4*)&conv_w[((size_t)dir * CONVDIM + ch) * 4];
  float cbv = conv_b[(size_t)dir * CONVDIM + ch];
  const bf16* xcol = ZX + rowbase * DINPROJ + DINNER + ch;  // stride DINPROJ
  int lg0 = c * CHUNK;   // global seq pos of chunk start
  float xm3 = (lg0 >= 3) ? (float)xcol[-3 * DINPROJ] : 0.0f;
  float xm2 = (lg0 >= 2) ? (float)xcol[-2 * DINPROJ] : 0.0f;
  float xm1 = (lg0 >= 1) ? (float)xcol[-1 * DINPROJ] : 0.0f;

  float Dv = Dparam[dir * NHEADS + h];

  float hs[16];
#pragma unroll
  for (int n = 0; n < 16; n++) hs[n] = 0.0f;

  bf16* yp = YSSM + rowbase * DINNER + ch;

#pragma unroll 4
  for (int l = 0; l < CHUNK; l++) {
    float dt = __shfl(dtv, l, 64);
    float da = __shfl(dav, l, 64);
    float xcur = (float)xcol[(size_t)l * DINPROJ];
    float conv = cbv + cwv[0]*xm3 + cwv[1]*xm2 + cwv[2]*xm1 + cwv[3]*xcur;
    xm3 = xm2; xm2 = xm1; xm1 = xcur;
    float xv = silu_f(conv);
    float4 bq[4], cq[4];
#pragma unroll
    for (int q = 0; q < 4; q++) {
      bq[q] = *(const float4*)&BCs[l][q * 4];
      cq[q] = *(const float4*)&BCs[l][16 + q * 4];
    }
    const float* Bv = (const float*)bq;
    const float* Cv = (const float*)cq;
    float dtx = dt * xv;
    float acc = 0.0f;
#pragma unroll
    for (int n = 0; n < 16; n++) {
      hs[n] = hs[n] * da + dtx * Bv[n];
      acc += hs[n] * Cv[n];
    }
    yp[(size_t)l * DINNER] = (bf16)(acc + Dv * xv);
  }

  float* he = HEND + ((size_t)g * NCHUNK + c) * 16 * 64;
#pragma unroll
  for (int n = 0; n < 16; n++) he[n * 64 + lane] = hs[n];
}

// ---------------- chunked SSM scan, pass 2: cross-chunk correction --------
__global__ __launch_bounds__(64) void scan2_kernel(
    const float* __restrict__ BCf, bf16* __restrict__ YSSM,
    const float* __restrict__ HEND, const float* __restrict__ APROD)
{
  int bid = blockIdx.x;
  int g = bid >> 4, c = bid & 15;
  if (c == 0) return;
  int dir = g >> 5, rem = g & 31;
  int b = rem >> 4, h = rem & 15;
  int lane = threadIdx.x;

  float hstart[16];
#pragma unroll
  for (int n = 0; n < 16; n++) hstart[n] = 0.0f;
  float w = 1.0f;
  for (int j = c - 1; j >= 0; j--) {
    const float* he = HEND + ((size_t)g * NCHUNK + j) * 16 * 64;
#pragma unroll
    for (int n = 0; n < 16; n++) hstart[n] += w * he[n * 64 + lane];
    w *= APROD[((size_t)g * NCHUNK + j) * 64 + 63];
  }

  size_t rowbase = (size_t)dir * ROWS + b * L_SEQ + c * CHUNK;
  bf16* yp = YSSM + rowbase * DINNER + h * HEADDIM + lane;
  float apv = APROD[((size_t)g * NCHUNK + c) * 64 + lane];

  __shared__ float Cs[CHUNK][20];
#pragma unroll
  for (int i = 0; i < 4; i++) {
    int l = i * 16 + (lane >> 2), f = lane & 3;
    float4 v = *(const float4*)&BCf[(rowbase + l) * 32 + 16 + f * 4];
    *(float4*)&Cs[l][f * 4] = v;
  }
  __syncthreads();

#pragma unroll 4
  for (int l = 0; l < CHUNK; l++) {
    float a = __shfl(apv, l, 64);
    float4 cq[4];
#pragma unroll
    for (int q = 0; q < 4; q++) cq[q] = *(const float4*)&Cs[l][q * 4];
    const float* Cv = (const float*)cq;
    float acc = 0.0f;
#pragma unroll
    for (int n = 0; n < 16; n++) acc += Cv[n] * hstart[n];
    float y = (float)yp[(size_t)l * DINNER];
    yp[(size_t)l * DINNER] = (bf16)(y + a * acc);
  }
}

// ------- gate (y already has D*x): y*silu(z) + RMS(1024), bf16 out -------
__global__ __launch_bounds__(256) void gatenorm_kernel(
    const bf16* __restrict__ YSSM, const bf16* __restrict__ ZX,
    const float* __restrict__ mnorm_w, bf16* __restrict__ YB)
{
  int r = blockIdx.x, dir = blockIdx.y, t = threadIdx.x;
  const bf16* y = YSSM + ((size_t)dir * ROWS + r) * DINNER;
  const bf16* z  = ZX  + ((size_t)dir * ROWS + r) * DINPROJ;
  int c = t * 4;
  bf16x4 yv4 = *(const bf16x4*)&y[c];
  bf16x4 zv4 = *(const bf16x4*)&z[c];
  float val[4];
#pragma unroll
  for (int q = 0; q < 4; q++)
    val[q] = (float)yv4[q] * silu_f((float)zv4[q]);
  float ss = val[0]*val[0] + val[1]*val[1] + val[2]*val[2] + val[3]*val[3];
  ss = wave_sum(ss);
  __shared__ float red[4];
  if ((t & 63) == 0) red[t >> 6] = ss;
  __syncthreads();
  float total = red[0] + red[1] + red[2] + red[3];
  float rs = 1.0f / sqrtf(total * (1.0f / DINNER) + 1e-5f);
  float4 wv = *(const float4*)&mnorm_w[dir * DINNER + c];
  bf16x4 o;
  o[0] = (bf16)(val[0] * rs * wv.x);
  o[1] = (bf16)(val[1] * rs * wv.y);
  o[2] = (bf16)(val[2] * rs * wv.z);
  o[3] = (bf16)(val[3] * rs * wv.w);
  *(bf16x4*)&YB[((size_t)dir * ROWS + r) * DINNER + c] = o;
}

// ------ combine (x += 0.5*(f+flip(b))*mask) + FFN RMS, bf16 out ------
__global__ __launch_bounds__(128) void combine_rms(
    const float* __restrict__ Xsrc, float* __restrict__ X,
    const float* __restrict__ P, const float* __restrict__ mask,
    const float* __restrict__ w, bf16* __restrict__ outb)
{
  int r = blockIdx.x, t = threadIdx.x;
  int b = r >> 10, l = r & 1023;
  int c = t * 4;
  float m = 0.5f * mask[r];
  float4 f0 = *(const float4*)&P[(size_t)r * DMODEL + c];
  float4 f1 = *(const float4*)&P[SLAB + (size_t)r * DMODEL + c];
  size_t fr = (size_t)(b * L_SEQ + (L_SEQ - 1 - l)) * DMODEL + c;
  float4 b0 = *(const float4*)&P[2 * SLAB + fr];
  float4 b1 = *(const float4*)&P[3 * SLAB + fr];
  float4 x = *(const float4*)&Xsrc[(size_t)r * DMODEL + c];
  x.x += m * (f0.x + f1.x + b0.x + b1.x);
  x.y += m * (f0.y + f1.y + b0.y + b1.y);
  x.z += m * (f0.z + f1.z + b0.z + b1.z);
  x.w += m * (f0.w + f1.w + b0.w + b1.w);
  *(float4*)&X[(size_t)r * DMODEL + c] = x;
  float ss = x.x*x.x + x.y*x.y + x.z*x.z + x.w*x.w;
  ss = wave_sum(ss);
  __shared__ float red[2];
  if ((t & 63) == 0) red[t >> 6] = ss;
  __syncthreads();
  float rs = 1.0f / sqrtf((red[0] + red[1]) * (1.0f / DMODEL) + 1e-6f);
  float4 wv = *(const float4*)&w[c];
  bf16x4 o;
  o[0] = (bf16)(x.x * rs * wv.x);
  o[1] = (bf16)(x.y * rs * wv.y);
  o[2] = (bf16)(x.z * rs * wv.z);
  o[3] = (bf16)(x.w * rs * wv.w);
  *(bf16x4*)&outb[(size_t)r * DMODEL + c] = o;
}

// ------ FFN2 splitK reduce (4 slabs) + bias + resid, then RMS ---
__global__ __launch_bounds__(128) void reduce_rms(
    float* __restrict__ X, const float* __restrict__ P,
    const float* __restrict__ bias, const float* __restrict__ w,
    const float* __restrict__ pe, const float* __restrict__ mask,
    bf16* __restrict__ outb, float* __restrict__ outf)
{
  int r = blockIdx.x, t = threadIdx.x;
  int c = t * 4;
  size_t off = (size_t)r * DMODEL + c;
  float4 a0 = *(const float4*)&P[off];
  float4 a1 = *(const float4*)&P[SLAB + off];
  float4 a2 = *(const float4*)&P[2 * SLAB + off];
  float4 a3 = *(const float4*)&P[3 * SLAB + off];
  float4 bi = *(const float4*)&bias[c];
  float4 x  = *(float4*)&X[off];
  x.x += a0.x + a1.x + a2.x + a3.x + bi.x;
  x.y += a0.y + a1.y + a2.y + a3.y + bi.y;
  x.z += a0.z + a1.z + a2.z + a3.z + bi.z;
  x.w += a0.w + a1.w + a2.w + a3.w + bi.w;
  *(float4*)&X[off] = x;
  float ss = x.x*x.x + x.y*x.y + x.z*x.z + x.w*x.w;
  ss = wave_sum(ss);
  __shared__ float red[2];
  if ((t & 63) == 0) red[t >> 6] = ss;
  __syncthreads();
  float rs = 1.0f / sqrtf((red[0] + red[1]) * (1.0f / DMODEL) + 1e-6f);
  float4 wv = *(const float4*)&w[c];
  float4 o;
  o.x = x.x*rs*wv.x; o.y = x.y*rs*wv.y; o.z = x.z*rs*wv.z; o.w = x.w*rs*wv.w;
  if (pe) {
    float4 p = *(const float4*)&pe[off];
    float m = mask[r];
    o.x = (o.x + p.x)*m; o.y = (o.y + p.y)*m; o.z = (o.z + p.z)*m; o.w = (o.w + p.w)*m;
  }
  if (outb) {
    bf16x4 ob = {(bf16)o.x, (bf16)o.y, (bf16)o.z, (bf16)o.w};
    *(bf16x4*)&outb[off] = ob;
  } else {
    *(float4*)&outf[off] = o;
  }
}

// ---------------- host ----------------
extern "C" void kernel_launch(void* const* d_in, const int* in_sizes, int n_in,
                              void* d_out, int out_size, void* d_ws, size_t ws_size,
                              hipStream_t stream)
{
  const float* in_x    = (const float*)d_in[0];
  const float* in_pe   = (const float*)d_in[1];
  const float* in_mask = (const float*)d_in[2];
  const float* W_in    = (const float*)d_in[3];
  const float* conv_w  = (const float*)d_in[4];
  const float* conv_b  = (const float*)d_in[5];
  const float* A_log   = (const float*)d_in[6];
  const float* Dparam  = (const float*)d_in[7];
  const float* dt_bias = (const float*)d_in[8];
  const float* mnorm_w = (const float*)d_in[9];
  const float* W_out   = (const float*)d_in[10];
  const float* nssm_w  = (const float*)d_in[11];
  const float* ffn_w1  = (const float*)d_in[12];
  const float* ffn_b1  = (const float*)d_in[13];
  const float* ffn_w2  = (const float*)d_in[14];
  const float* ffn_b2  = (const float*)d_in[15];
  const float* nffn_w  = (const float*)d_in[16];
  const float* final_w = (const float*)d_in[17];

  if (ws_size < 126287872) return;

  // workspace layout. DOUT (4 f32 slabs, 16.78MB) OVERLAYS ZXb (verified).
  char* ws = (char*)d_ws;
  float* XBUF  = (float*)(ws + 0);            //  4,194,304
  bf16*  SBUF  = (bf16*) (ws + 4194304);      //  2,097,152
  bf16*  ZXb   = (bf16*) (ws + 6291456);      // 17,170,432
  float* DOUTf = (float*)(ws + 6291456);      // 16,777,216 (alias of ZXb)
  float* DTRAW = (float*)(ws + 23461888);     //    262,144
  float* BCf   = (float*)(ws + 23724032);     //    524,288
  float* DTb   = (float*)(ws + 24248320);     //    262,144
  float* DAb   = (float*)(ws + 24510464);     //    262,144
  bf16*  YSSMb = (bf16*) (ws + 24772608);     //  8,388,608
  bf16*  YB    = (bf16*) (ws + 33161216);     //  8,388,608
  bf16*  MID   = (bf16*) (ws + 41549824);     //  8,388,608
  float* HEND  = (float*)(ws + 49938432);     //  4,194,304
  float* APROD = (float*)(ws + 54132736);     //    262,144
  bf16*  WTINa = (bf16*) (ws + 62783488);     // 25,755,648
  bf16*  WTOUTa= (bf16*) (ws + 88539136);     // 12,582,912
  bf16*  WT1a  = (bf16*) (ws + 101122048);    // 12,582,912
  bf16*  WT2a  = (bf16*) (ws + 113704960);    // 12,582,912 -> 126,287,872

  transpose_all<<<7776, 256, 0, stream>>>(W_in, W_out, ffn_w1, ffn_w2,
                                          WTINa, WTOUTa, WT1a, WT2a);
  rms_kernel<<<ROWS, 128, 0, stream>>>(in_x, nssm_w, in_pe, in_mask, SBUF);

  for (int layer = 0; layer < 6; layer++) {
    const bf16* WTIN  = WTINa  + (size_t)layer * 2 * DMODEL * DINPROJ;
    const bf16* WTOUT = WTOUTa + (size_t)layer * 2 * DINNER * DMODEL;
    const bf16* WT1   = WT1a   + (size_t)layer * DMODEL * FFN_DIM;
    const bf16* WT2   = WT2a   + (size_t)layer * FFN_DIM * DMODEL;
    const float* cw_l = conv_w + (size_t)layer * 2 * CONVDIM * 4;
    const float* cb_l = conv_b + (size_t)layer * 2 * CONVDIM;

    gemm_tile<128, 128, 4, 4, 3><<<dim3(16, 17, 2), 256, 0, stream>>>(
        SBUF, WTIN, DTRAW, ZXb, ROWS, DINPROJ, DMODEL, DMODEL, DMODEL,
        0L, (long)DINPROJ * DMODEL, (long)ROWS * DINPROJ, 1, 1, nullptr);
    convdt_bc<<<dim3(ROWS, 2), 64, 0, stream>>>(
        ZXb, DTRAW, BCf, DTb, DAb, cw_l, cb_l,
        dt_bias + layer * 2 * NHEADS, A_log + layer * 2 * NHEADS);
    scan1_kernel<<<1024, 64, 0, stream>>>(
        ZXb, BCf, DTb, DAb, YSSMb, HEND, APROD, cw_l, cb_l,
        Dparam + layer * 2 * NHEADS);
    scan2_kernel<<<1024, 64, 0, stream>>>(BCf, YSSMb, HEND, APROD);
    gatenorm_kernel<<<dim3(ROWS, 2), 256, 0, stream>>>(
        YSSMb, ZXb, mnorm_w + layer * 2 * DINNER, YB);
    // W_out: z = dir*2 + ks (kspl=2, K=512 each) -> 512 blocks, 2/CU
    gemm_tile<128, 64, 4, 2, 0><<<dim3(16, 8, 4), 256, 0, stream>>>(
        YB, WTOUT, DOUTf, nullptr, ROWS, DMODEL, 512, DINNER, DINNER,
        (long)ROWS * DINNER, (long)DMODEL * DINNER, (long)SLAB, 0, 2, nullptr);
    combine_rms<<<ROWS, 128, 0, stream>>>(
        layer == 0 ? in_x : XBUF, XBUF, DOUTf, in_mask, nffn_w + layer * DMODEL, SBUF);

    // FFN
    gemm_tile<128, 64, 4, 2, 1><<<dim3(16, 32, 1), 256, 0, stream>>>(
        SBUF, WT1, nullptr, MID, ROWS, FFN_DIM, DMODEL, DMODEL, DMODEL,
        0L, 0L, 0L, 0, 1, ffn_b1 + layer * FFN_DIM);
    // FFN2: kspl=4 (K=512 each) -> 512 blocks, 2/CU
    gemm_tile<128, 64, 4, 2, 0><<<dim3(16, 8, 4), 256, 0, stream>>>(
        MID, WT2, DOUTf, nullptr, ROWS, DMODEL, 512, FFN_DIM, FFN_DIM,
        0L, 0L, (long)SLAB, 0, 4, nullptr);
    if (layer < 5) {
      reduce_rms<<<ROWS, 128, 0, stream>>>(
          XBUF, DOUTf, ffn_b2 + layer * DMODEL, nssm_w + (layer + 1) * DMODEL,
          in_pe, in_mask, SBUF, nullptr);
    } else {
      reduce_rms<<<ROWS, 128, 0, stream>>>(
          XBUF, DOUTf, ffn_b2 + layer * DMODEL, final_w,
          nullptr, nullptr, nullptr, (float*)d_out);
    }
  }
}